// Round 2
// baseline (850.401 us; speedup 1.0000x reference)
//
#include <hip/hip_runtime.h>
#include <stdint.h>

typedef unsigned short u16;
typedef short v8s __attribute__((ext_vector_type(8)));
typedef float v4f __attribute__((ext_vector_type(4)));

__device__ __forceinline__ float bf2f(u16 u) {
  union { unsigned int i; float f; } v; v.i = ((unsigned int)u) << 16; return v.f;
}
__device__ __forceinline__ u16 f2bf(float f) {
  union { float f; unsigned int i; } v; v.f = f;
  unsigned int r = v.i + 0x7FFFu + ((v.i >> 16) & 1u);
  return (u16)(r >> 16);
}

// async global->LDS: dest = wave-uniform base + lane*16
#define GLOAD16(g, l) __builtin_amdgcn_global_load_lds( \
    (__attribute__((address_space(1))) void*)(g), \
    (__attribute__((address_space(3))) void*)(l), 16, 0, 0)

// ---------------------------------------------------------------------------
// dtype probe: ln_in_g is all-ones. bf16 -> u16[0]==0x3F80 ; fp32 -> u16[0]==0
// ---------------------------------------------------------------------------
__global__ void detect_dtype(const u16* __restrict__ ln_g, int* __restrict__ flags) {
  if (threadIdx.x == 0 && blockIdx.x == 0) {
    flags[0] = (ln_g[0] != 0x3F80) ? 1 : 0;  // is_f32
    flags[1] = 0;                            // constant "bf16" flag for intermediates
  }
}

// ---------------------------------------------------------------------------
// convert all float tensors to canonical bf16 (table-driven, one launch)
// ---------------------------------------------------------------------------
#define NCONV 23
struct ConvTab {
  const void* src[NCONV];
  void* dst[NCONV];
  int n[NCONV];
};

__launch_bounds__(256)
__global__ void convert_inputs(ConvTab tab, const int* __restrict__ flags) {
  const int t = blockIdx.y;
  const int n4 = tab.n[t] >> 2;
  const int f32 = flags[0];
  const float4* sf = (const float4*)tab.src[t];
  const ushort4* sb = (const ushort4*)tab.src[t];
  ushort4* d = (ushort4*)tab.dst[t];
  for (int i = blockIdx.x * 256 + threadIdx.x; i < n4; i += gridDim.x * 256) {
    ushort4 o;
    if (f32) {
      float4 v = sf[i];
      o.x = f2bf(v.x); o.y = f2bf(v.y); o.z = f2bf(v.z); o.w = f2bf(v.w);
    } else {
      o = sb[i];
    }
    d[i] = o;
  }
}

// ---------------------------------------------------------------------------
// BT-GEMM: C[M,N] = A[M,K] @ B'[N,K]^T, bf16 inputs, fp32 accum.
// A is split at ksplit between A0/A1 (virtual concat).
// MODE 0: store fp32. MODE 1: fp32 * gate[seg][b][col]. MODE 2 (PV): bf16 into
//         xcat at [(b*1024+row)*512 + h*64 + col], batch = blockIdx.z = b*8+h.
// ---------------------------------------------------------------------------
template<int WM, int WN, int MODE>
__launch_bounds__(WM*WN*64)
__global__ void gemm_bt(const u16* __restrict__ A0, int lda0,
                        const u16* __restrict__ A1, int lda1, int ksplit,
                        const u16* __restrict__ Bm, int ldb,
                        float* __restrict__ Cf, u16* __restrict__ Cb, int ldc, int K,
                        const float* __restrict__ gate,
                        long batchA, long batchB) {
  constexpr int BM = WM*64, BN = WN*64, BK = 32;
  constexpr int NT = WM*WN*64;
  constexpr int AC = BM*4;   // 16B chunks in A tile
  constexpr int BC = BN*4;
  static_assert(AC % NT == 0 && BC % NT == 0, "chunk split");
  __shared__ u16 As[BM*BK];
  __shared__ u16 Bs[BN*BK];

  const int tid = threadIdx.x;
  const int wid = tid >> 6, lane = tid & 63;
  const int lm = lane & 15, quad = lane >> 4;
  const int wm = wid % WM, wn = wid / WM;
  const int m0 = blockIdx.x * BM, n0 = blockIdx.y * BN;
  const u16* Ab = A0 + (size_t)blockIdx.z * batchA;
  const u16* Bb = Bm + (size_t)blockIdx.z * batchB;

  v4f acc[4][4];
  #pragma unroll
  for (int i = 0; i < 4; i++)
    #pragma unroll
    for (int j = 0; j < 4; j++) acc[i][j] = v4f{0.f, 0.f, 0.f, 0.f};

  for (int k0 = 0; k0 < K; k0 += BK) {
    __syncthreads();
    #pragma unroll
    for (int i = 0; i < AC/NT; ++i) {
      int c = i*NT + tid;
      int row = c >> 2;
      int kg = k0 + ((c & 3) << 3);
      const u16* src = (kg < ksplit) ? (Ab + (size_t)(m0 + row) * lda0 + kg)
                                     : (A1 + (size_t)(m0 + row) * lda1 + (kg - ksplit));
      GLOAD16(src, &As[(i*NT + (wid << 6)) * 8]);
    }
    #pragma unroll
    for (int i = 0; i < BC/NT; ++i) {
      int c = i*NT + tid;
      int row = c >> 2;
      int kg = k0 + ((c & 3) << 3);
      const u16* src = Bb + (size_t)(n0 + row) * ldb + kg;
      GLOAD16(src, &Bs[(i*NT + (wid << 6)) * 8]);
    }
    __syncthreads();
    v8s af[4], bfr[4];
    #pragma unroll
    for (int t = 0; t < 4; t++)
      af[t] = *(const v8s*)&As[(wm*64 + t*16 + lm)*BK + quad*8];
    #pragma unroll
    for (int t = 0; t < 4; t++)
      bfr[t] = *(const v8s*)&Bs[(wn*64 + t*16 + lm)*BK + quad*8];
    #pragma unroll
    for (int i = 0; i < 4; i++)
      #pragma unroll
      for (int j = 0; j < 4; j++)
        acc[i][j] = __builtin_amdgcn_mfma_f32_16x16x32_bf16(af[i], bfr[j], acc[i][j], 0, 0, 0);
  }

  #pragma unroll
  for (int i = 0; i < 4; i++) {
    #pragma unroll
    for (int j = 0; j < 4; j++) {
      int colw = wn*64 + j*16 + lm;
      #pragma unroll
      for (int r = 0; r < 4; r++) {
        int roww = wm*64 + i*16 + quad*4 + r;
        float v = acc[i][j][r];
        if (MODE == 0) {
          Cf[(size_t)(m0 + roww) * ldc + (n0 + colw)] = v;
        } else if (MODE == 1) {
          int col = n0 + colw, row = m0 + roww;
          float g = gate[(((col >> 9) << 2) + (row >> 10)) * 512 + (col & 511)];
          Cf[(size_t)row * ldc + col] = v * g;
        } else {
          int bz = blockIdx.z >> 3, hz = blockIdx.z & 7;
          Cb[(((size_t)(bz << 10) + (m0 + roww)) << 9) + (hz << 6) + colw] = f2bf(v);
        }
      }
    }
  }
}

// ---------------------------------------------------------------------------
// bf16 transpose: src [R][C] -> dst [C][R], batched via blockIdx.z (stride R*C)
// ---------------------------------------------------------------------------
__launch_bounds__(256)
__global__ void transpose_bf16(const u16* __restrict__ src, u16* __restrict__ dst,
                               int R, int C) {
  __shared__ u16 t[64][65];
  const int c0 = blockIdx.x << 6, r0 = blockIdx.y << 6;
  const size_t bo = (size_t)blockIdx.z * R * C;
  const int tx = threadIdx.x & 63, ty = threadIdx.x >> 6;
  #pragma unroll
  for (int i = 0; i < 16; i++) {
    int r = (i << 2) + ty;
    t[r][tx] = src[bo + (size_t)(r0 + r) * C + c0 + tx];
  }
  __syncthreads();
  #pragma unroll
  for (int i = 0; i < 16; i++) {
    int c = (i << 2) + ty;
    dst[bo + (size_t)(c0 + c) * R + r0 + tx] = t[tx][c];
  }
}

// ---------------------------------------------------------------------------
// mask compress: 9 int32 [B,N,N] disjoint masks -> u8 cat (0=none,1=ent,k+2=type k)
// ---------------------------------------------------------------------------
__launch_bounds__(256)
__global__ void mask_compress(const int4* __restrict__ me, const int4* __restrict__ mt,
                              uchar4* __restrict__ cat) {
  const int idx = blockIdx.x * 256 + threadIdx.x;
  int4 e = me[idx];
  int c0 = e.x, c1 = e.y, c2 = e.z, c3 = e.w;
  #pragma unroll
  for (int k = 0; k < 8; k++) {
    int4 m = mt[(size_t)k * 1048576 + idx];
    c0 += (k + 2) * m.x; c1 += (k + 2) * m.y; c2 += (k + 2) * m.z; c3 += (k + 2) * m.w;
  }
  uchar4 o;
  o.x = (unsigned char)c0; o.y = (unsigned char)c1;
  o.z = (unsigned char)c2; o.w = (unsigned char)c3;
  cat[idx] = o;
}

// ---------------------------------------------------------------------------
// gates: per (t,b): t1=elu(q@W_fc); m_t=t1@w_dc[t]; gates[s]=m_t@W_{q,k,v}c
// ---------------------------------------------------------------------------
__launch_bounds__(256)
__global__ void compute_gates(const u16* __restrict__ q, const u16* __restrict__ Wfc,
                              const u16* __restrict__ wdc,
                              const u16* __restrict__ Wqc, const u16* __restrict__ Wkc,
                              const u16* __restrict__ Wvc,
                              float* __restrict__ gates) {
  const int t = blockIdx.x >> 2, b = blockIdx.x & 3;
  __shared__ float qs[512];
  __shared__ float t1[1024];
  __shared__ float mts[512];
  const int tid = threadIdx.x;
  for (int i = tid; i < 512; i += 256) qs[i] = bf2f(q[b * 512 + i]);
  __syncthreads();
  {
    float a0 = 0, a1 = 0, a2 = 0, a3 = 0;
    for (int k = 0; k < 512; k++) {
      ushort4 wv = *(const ushort4*)&Wfc[(size_t)k * 1024 + tid * 4];
      float qk = qs[k];
      a0 += qk * bf2f(wv.x); a1 += qk * bf2f(wv.y);
      a2 += qk * bf2f(wv.z); a3 += qk * bf2f(wv.w);
    }
    t1[tid*4+0] = a0 > 0 ? a0 : __expf(a0) - 1.0f;
    t1[tid*4+1] = a1 > 0 ? a1 : __expf(a1) - 1.0f;
    t1[tid*4+2] = a2 > 0 ? a2 : __expf(a2) - 1.0f;
    t1[tid*4+3] = a3 > 0 ? a3 : __expf(a3) - 1.0f;
  }
  __syncthreads();
  {
    float a0 = 0, a1 = 0;
    const u16* wd = wdc + (size_t)t * 1024 * 512;
    for (int k = 0; k < 1024; k++) {
      ushort2 wv = *(const ushort2*)&wd[(size_t)k * 512 + tid * 2];
      float tk = t1[k];
      a0 += tk * bf2f(wv.x); a1 += tk * bf2f(wv.y);
    }
    mts[tid*2] = a0; mts[tid*2+1] = a1;
  }
  __syncthreads();
  #pragma unroll
  for (int s = 0; s < 3; s++) {
    const u16* W = (s == 0) ? Wqc : ((s == 1) ? Wkc : Wvc);
    float a0 = 0, a1 = 0;
    for (int k = 0; k < 512; k++) {
      ushort2 wv = *(const ushort2*)&W[(size_t)k * 512 + tid * 2];
      float mk = mts[k];
      a0 += mk * bf2f(wv.x); a1 += mk * bf2f(wv.y);
    }
    float* gp = gates + (((t * 3 + s) * 4 + b) << 9);
    gp[tid*2] = a0; gp[tid*2+1] = a1;
  }
}

// ---------------------------------------------------------------------------
// LayerNorm rows: W = NE*256, segments via blockIdx.y (qkv fusion)
// flags[0]!=0 -> write fp32 to dst; else bf16.
// ---------------------------------------------------------------------------
template<int NE>
__launch_bounds__(256)
__global__ void ln_rows(const float* __restrict__ src, int sstride, int ssegoff,
                        void* __restrict__ dst, int dstride, int dsegoff,
                        const int* __restrict__ flagp,
                        const u16* __restrict__ g0, const u16* __restrict__ b0,
                        const u16* __restrict__ g1, const u16* __restrict__ b1,
                        const u16* __restrict__ g2, const u16* __restrict__ b2) {
  constexpr int W = NE * 256;
  const int row = blockIdx.x, seg = blockIdx.y;
  const u16* g  = (seg == 0) ? g0 : ((seg == 1) ? g1 : g2);
  const u16* bb = (seg == 0) ? b0 : ((seg == 1) ? b1 : b2);
  const float* x = src + (size_t)row * sstride + (size_t)seg * ssegoff;
  const size_t dbase = (size_t)row * dstride + (size_t)seg * dsegoff;
  const int f32out = *flagp;
  const int tid = threadIdx.x;
  const int wid = tid >> 6, lane = tid & 63;
  __shared__ float red[4];
  float v[NE];
  float s = 0.f;
  #pragma unroll
  for (int i = 0; i < NE; i++) { v[i] = x[tid + (i << 8)]; s += v[i]; }
  #pragma unroll
  for (int off = 32; off; off >>= 1) s += __shfl_xor(s, off, 64);
  if (lane == 0) red[wid] = s;
  __syncthreads();
  float mean = (red[0] + red[1] + red[2] + red[3]) * (1.0f / W);
  float q = 0.f;
  #pragma unroll
  for (int i = 0; i < NE; i++) { float dd = v[i] - mean; q += dd * dd; }
  __syncthreads();
  #pragma unroll
  for (int off = 32; off; off >>= 1) q += __shfl_xor(q, off, 64);
  if (lane == 0) red[wid] = q;
  __syncthreads();
  float var = (red[0] + red[1] + red[2] + red[3]) * (1.0f / W);
  float rs = rsqrtf(var + 1e-12f);
  #pragma unroll
  for (int i = 0; i < NE; i++) {
    int c = tid + (i << 8);
    float y = (v[i] - mean) * rs * bf2f(g[c]) + bf2f(bb[c]);
    if (f32out) ((float*)dst)[dbase + c] = y;
    else        ((u16*)dst)[dbase + c] = f2bf(y);
  }
}

// ---------------------------------------------------------------------------
// a_src[b,h,m,n] = sum_d xq[b,n,h*64+d]*Watt[m][d]; a_dst from xk, Watt[m][64+d]
// ---------------------------------------------------------------------------
__launch_bounds__(256)
__global__ void att_proj(const u16* __restrict__ xq, const u16* __restrict__ xk,
                         const u16* __restrict__ Watt,
                         float* __restrict__ asrc, float* __restrict__ adst) {
  __shared__ float w[9][128];
  const int tid = threadIdx.x;
  for (int i = tid; i < 9 * 128; i += 256) w[i / 128][i % 128] = bf2f(Watt[i]);
  __syncthreads();
  const int wid = tid >> 6, lane = tid & 63;
  const int row = blockIdx.x * 4 + wid;
  const int b = row >> 10, n = row & 1023;
  v8s q8 = *(const v8s*)&xq[(size_t)row * 512 + lane * 8];
  v8s k8 = *(const v8s*)&xk[(size_t)row * 512 + lane * 8];
  float qf[8], kf[8];
  #pragma unroll
  for (int j = 0; j < 8; j++) { qf[j] = bf2f((u16)q8[j]); kf[j] = bf2f((u16)k8[j]); }
  const int h = lane >> 3, lh = lane & 7;
  #pragma unroll
  for (int m = 0; m < 9; m++) {
    float ps = 0.f, pd = 0.f;
    #pragma unroll
    for (int j = 0; j < 8; j++) {
      ps += qf[j] * w[m][lh * 8 + j];
      pd += kf[j] * w[m][64 + lh * 8 + j];
    }
    #pragma unroll
    for (int off = 1; off < 8; off <<= 1) {
      ps += __shfl_xor(ps, off, 64);
      pd += __shfl_xor(pd, off, 64);
    }
    if (lh == 0) {
      size_t base = ((size_t)((b * 8 + h) * 9 + m) << 10) + n;
      asrc[base] = ps;
      adst[base] = pd;
    }
  }
}

// ---------------------------------------------------------------------------
// score + masked softmax -> P bf16 [32][1024][1024]
// ---------------------------------------------------------------------------
__launch_bounds__(256)
__global__ void score_softmax(const unsigned char* __restrict__ cat,
                              const float* __restrict__ asrc,
                              const float* __restrict__ adst,
                              u16* __restrict__ P) {
  const int bh = blockIdx.y;
  const int b = bh >> 3;
  const int i0 = blockIdx.x << 6;
  __shared__ float adst_s[9 * 1024];
  __shared__ float asrc_s[64 * 9];
  const int tid = threadIdx.x;
  const float* ad = adst + (size_t)bh * 9216;
  for (int i = tid; i < 9216; i += 256) adst_s[i] = ad[i];
  const float* as = asrc + (size_t)bh * 9216;
  for (int i = tid; i < 576; i += 256) {
    int r = i / 9, m = i % 9;
    asrc_s[i] = as[(m << 10) + i0 + r];
  }
  __syncthreads();
  const int wid = tid >> 6, lane = tid & 63;
  for (int ir = wid; ir < 64; ir += 4) {
    const int i = i0 + ir;
    const unsigned int* crow = (const unsigned int*)(cat + (((size_t)(b << 10) + i) << 10));
    float z[16];
    float mx = -1e30f;
    #pragma unroll
    for (int it = 0; it < 4; it++) {
      unsigned int c4 = crow[(it << 6) + lane];
      int jb = (it << 8) + (lane << 2);
      #pragma unroll
      for (int s = 0; s < 4; s++) {
        int c = (c4 >> (s * 8)) & 255;
        float zz = -1e30f;
        if (c > 0) {
          int m = c - 1;
          float sc = asrc_s[ir * 9 + m] + adst_s[(m << 10) + jb + s];
          zz = (sc > 0.f) ? sc : 0.01f * sc;
          mx = fmaxf(mx, zz);
        }
        z[it * 4 + s] = zz;
      }
    }
    #pragma unroll
    for (int off = 32; off; off >>= 1) mx = fmaxf(mx, __shfl_xor(mx, off, 64));
    float sum = 0.f;
    #pragma unroll
    for (int u = 0; u < 16; u++) {
      float e = (z[u] > -1e29f) ? __expf(z[u] - mx) : 0.f;
      z[u] = e; sum += e;
    }
    #pragma unroll
    for (int off = 32; off; off >>= 1) sum += __shfl_xor(sum, off, 64);
    float inv = 1.0f / (sum + 1e-13f);
    u16* prow = P + (((size_t)bh << 10) + i) * 1024;
    #pragma unroll
    for (int it = 0; it < 4; it++) {
      int jb = (it << 8) + (lane << 2);
      ushort4 o;
      o.x = f2bf(z[it * 4 + 0] * inv);
      o.y = f2bf(z[it * 4 + 1] * inv);
      o.z = f2bf(z[it * 4 + 2] * inv);
      o.w = f2bf(z[it * 4 + 3] * inv);
      *(ushort4*)&prow[jb] = o;
    }
  }
}

// ---------------------------------------------------------------------------
extern "C" void kernel_launch(void* const* d_in, const int* in_sizes, int n_in,
                              void* d_out, int out_size, void* d_ws, size_t ws_size,
                              hipStream_t stream) {
  char* wptr = (char*)d_ws;
  auto alloc = [&](size_t bytes) {
    char* p = wptr; wptr += (bytes + 255) & ~(size_t)255; return p;
  };
  int* flags     = (int*)alloc(256);
  uint8_t* cat   = (uint8_t*)alloc(4ull << 20);
  u16* dwT       = (u16*)alloc(1024ull*1024*2);
  u16* wqkvT     = (u16*)alloc(1536ull*1024*2);
  u16* wuT       = (u16*)alloc(512ull*1024*2);
  float* gates   = (float*)alloc(2ull*3*4*512*4);
  // canonical bf16 copies of the 23 float tensors
  static const int cn[NCONV] = {
    2097152, 2048, 524288, 1048576, 1048576, 1024, 1024,
    524288, 524288, 524288, 262144, 262144, 262144,
    512, 512, 512, 512, 512, 512, 1152, 524288, 512, 512 };
  u16* canon[NCONV];
  for (int i = 0; i < NCONV; i++) canon[i] = (u16*)alloc((size_t)cn[i] * 2);
  // 64 MB union: ie_pre/qkv_pre/ie (phase 1) -> P (phase 2) -> u_pre (phase 3)
  char* U = alloc(64ull << 20);
  float* ie_pre  = (float*)U;                       // 16 MB
  float* qkv_pre = (float*)(U + (16ull << 20));     // 24 MB
  u16*   ie      = (u16*)(U + (40ull << 20));       //  8 MB
  u16*   P       = (u16*)U;                         // 64 MB
  float* u_pre   = (float*)U;                       //  8 MB
  u16* xqkv      = (u16*)alloc(3ull*4096*512*2);
  float* asrc    = (float*)alloc(32ull*9*1024*4);
  float* adst    = (float*)alloc(32ull*9*1024*4);
  u16* xvT       = (u16*)alloc(32ull*64*1024*2);
  u16* xcat      = (u16*)alloc(4096ull*512*2);
  u16* node_enc  = (u16*)alloc(4096ull*512*2);

  const int* mask_e = (const int*)d_in[23];
  const int* mask_t = (const int*)d_in[24];

  detect_dtype<<<1, 64, 0, stream>>>((const u16*)d_in[5], flags);

  ConvTab tab;
  for (int i = 0; i < NCONV; i++) {
    tab.src[i] = d_in[i]; tab.dst[i] = canon[i]; tab.n[i] = cn[i];
  }
  convert_inputs<<<dim3(64, NCONV), 256, 0, stream>>>(tab, flags);

  const u16* c_node = canon[0];
  const u16* c_q    = canon[1];
  const u16* c_Wfc  = canon[2];
  const u16* c_wdc  = canon[3];
  const u16* c_dw   = canon[4];
  const u16 *c_lin_g = canon[5], *c_lin_b = canon[6];
  const u16 *c_Wqv = canon[7], *c_Wkv = canon[8], *c_Wvv = canon[9];
  const u16 *c_Wqc = canon[10], *c_Wkc = canon[11], *c_Wvc = canon[12];
  const u16 *c_lq_g = canon[13], *c_lq_b = canon[14];
  const u16 *c_lk_g = canon[15], *c_lk_b = canon[16];
  const u16 *c_lv_g = canon[17], *c_lv_b = canon[18];
  const u16* c_Watt = canon[19];
  const u16* c_Wu   = canon[20];
  const u16 *c_lo_g = canon[21], *c_lo_b = canon[22];

  mask_compress<<<4096, 256, 0, stream>>>((const int4*)mask_e, (const int4*)mask_t,
                                          (uchar4*)cat);
  transpose_bf16<<<dim3(16,16,1), 256, 0, stream>>>(c_dw, dwT, 1024, 1024);
  transpose_bf16<<<dim3(8,16,1),  256, 0, stream>>>(c_Wqv, wqkvT,             1024, 512);
  transpose_bf16<<<dim3(8,16,1),  256, 0, stream>>>(c_Wkv, wqkvT + 512*1024,  1024, 512);
  transpose_bf16<<<dim3(8,16,1),  256, 0, stream>>>(c_Wvv, wqkvT + 1024*1024, 1024, 512);
  transpose_bf16<<<dim3(8,16,1),  256, 0, stream>>>(c_Wu,  wuT,               1024, 512);
  compute_gates<<<8, 256, 0, stream>>>(c_q, c_Wfc, c_wdc, c_Wqc, c_Wkc, c_Wvc, gates);

  const u16* ne_cur = c_node;
  for (int t = 0; t < 2; ++t) {
    gemm_bt<2,2,0><<<dim3(32,8,1), 256, 0, stream>>>(
        ne_cur, 512, c_node, 512, 512, dwT, 1024,
        ie_pre, (u16*)nullptr, 1024, 1024, (const float*)nullptr, 0, 0);
    ln_rows<4><<<dim3(4096,1), 256, 0, stream>>>(
        ie_pre, 1024, 0, ie, 1024, 0, flags + 1,
        c_lin_g, c_lin_b, c_lin_g, c_lin_b, c_lin_g, c_lin_b);
    gemm_bt<2,2,1><<<dim3(32,12,1), 256, 0, stream>>>(
        ie, 1024, ie, 1024, 1024, wqkvT, 1024,
        qkv_pre, (u16*)nullptr, 1536, 1024, gates + t*6144, 0, 0);
    ln_rows<2><<<dim3(4096,3), 256, 0, stream>>>(
        qkv_pre, 1536, 512, xqkv, 512, 4096*512, flags + 1,
        c_lq_g, c_lq_b, c_lk_g, c_lk_b, c_lv_g, c_lv_b);
    att_proj<<<1024, 256, 0, stream>>>(xqkv, xqkv + 4096*512, c_Watt, asrc, adst);
    transpose_bf16<<<dim3(8,16,4), 256, 0, stream>>>(xqkv + 2*4096*512, xvT, 1024, 512);
    score_softmax<<<dim3(16,32,1), 256, 0, stream>>>(cat, asrc, adst, P);
    gemm_bt<4,1,2><<<dim3(4,1,32), 256, 0, stream>>>(
        P, 1024, P, 1024, 1024, xvT, 1024,
        (float*)nullptr, xcat, 512, 1024, (const float*)nullptr, 1048576, 65536);
    gemm_bt<2,2,0><<<dim3(32,4,1), 256, 0, stream>>>(
        ne_cur, 512, xcat, 512, 512, wuT, 1024,
        u_pre, (u16*)nullptr, 512, 1024, (const float*)nullptr, 0, 0);
    void* dst = (t == 1) ? d_out : (void*)node_enc;
    const int* fl = (t == 1) ? flags : (flags + 1);
    ln_rows<2><<<dim3(4096,1), 256, 0, stream>>>(
        u_pre, 512, 0, dst, 512, 0, fl,
        c_lo_g, c_lo_b, c_lo_g, c_lo_b, c_lo_g, c_lo_b);
    ne_cur = node_enc;
  }
  (void)in_sizes; (void)n_in; (void)out_size; (void)ws_size;
}

// Round 3
// 720.053 us; speedup vs baseline: 1.1810x; 1.1810x over previous
//
#include <hip/hip_runtime.h>
#include <stdint.h>

typedef unsigned short u16;
typedef short v8s __attribute__((ext_vector_type(8)));
typedef float v4f __attribute__((ext_vector_type(4)));

__device__ __forceinline__ float bf2f(u16 u) {
  union { unsigned int i; float f; } v; v.i = ((unsigned int)u) << 16; return v.f;
}
__device__ __forceinline__ u16 f2bf(float f) {
  union { float f; unsigned int i; } v; v.f = f;
  unsigned int r = v.i + 0x7FFFu + ((v.i >> 16) & 1u);
  return (u16)(r >> 16);
}

// async global->LDS: dest = wave-uniform base + lane*16
#define GLOAD16(g, l) __builtin_amdgcn_global_load_lds( \
    (__attribute__((address_space(1))) void*)(g), \
    (__attribute__((address_space(3))) void*)(l), 16, 0, 0)

// ---------------------------------------------------------------------------
// dtype probe: ln_in_g is all-ones. bf16 -> u16[0]==0x3F80 ; fp32 -> u16[0]==0
// ---------------------------------------------------------------------------
__global__ void detect_dtype(const u16* __restrict__ ln_g, int* __restrict__ flags) {
  if (threadIdx.x == 0 && blockIdx.x == 0) {
    flags[0] = (ln_g[0] != 0x3F80) ? 1 : 0;  // is_f32
    flags[1] = 0;                            // constant "bf16" flag for intermediates
  }
}

// ---------------------------------------------------------------------------
// convert all float tensors to canonical bf16 (table-driven, one launch)
// ---------------------------------------------------------------------------
#define NCONV 23
struct ConvTab {
  const void* src[NCONV];
  void* dst[NCONV];
  int n[NCONV];
};

__launch_bounds__(256)
__global__ void convert_inputs(ConvTab tab, const int* __restrict__ flags) {
  const int t = blockIdx.y;
  const int n4 = tab.n[t] >> 2;
  const int f32 = flags[0];
  const float4* sf = (const float4*)tab.src[t];
  const ushort4* sb = (const ushort4*)tab.src[t];
  ushort4* d = (ushort4*)tab.dst[t];
  for (int i = blockIdx.x * 256 + threadIdx.x; i < n4; i += gridDim.x * 256) {
    ushort4 o;
    if (f32) {
      float4 v = sf[i];
      o.x = f2bf(v.x); o.y = f2bf(v.y); o.z = f2bf(v.z); o.w = f2bf(v.w);
    } else {
      o = sb[i];
    }
    d[i] = o;
  }
}

// ---------------------------------------------------------------------------
// BT-GEMM: C[M,N] = A[M,K] @ B'[N,K]^T, bf16 inputs, fp32 accum.
// Each wave owns a 64x64 macro-tile (4x4 MFMA frags); block = WM x WN waves.
// MODE 0: store fp32. MODE 1: fp32 * gate[seg][b][col]. MODE 2 (PV): bf16 into
//         xcat at [(b*1024+row)*512 + h*64 + col], batch = blockIdx.z = b*8+h.
// ---------------------------------------------------------------------------
template<int WM, int WN, int MODE>
__launch_bounds__(WM*WN*64)
__global__ void gemm_bt(const u16* __restrict__ A0, int lda0,
                        const u16* __restrict__ A1, int lda1, int ksplit,
                        const u16* __restrict__ Bm, int ldb,
                        float* __restrict__ Cf, u16* __restrict__ Cb, int ldc, int K,
                        const float* __restrict__ gate,
                        long batchA, long batchB) {
  constexpr int BM = WM*64, BN = WN*64, BK = 32;
  constexpr int NT = WM*WN*64;
  constexpr int AC = BM*4;   // 16B chunks in A tile
  constexpr int BC = BN*4;
  static_assert(AC % NT == 0 && BC % NT == 0, "chunk split");
  __shared__ u16 As[BM*BK];
  __shared__ u16 Bs[BN*BK];

  const int tid = threadIdx.x;
  const int wid = tid >> 6, lane = tid & 63;
  const int lm = lane & 15, quad = lane >> 4;
  const int wm = wid % WM, wn = wid / WM;
  const int m0 = blockIdx.x * BM, n0 = blockIdx.y * BN;
  const u16* Ab = A0 + (size_t)blockIdx.z * batchA;
  const u16* Bb = Bm + (size_t)blockIdx.z * batchB;

  v4f acc[4][4];
  #pragma unroll
  for (int i = 0; i < 4; i++)
    #pragma unroll
    for (int j = 0; j < 4; j++) acc[i][j] = v4f{0.f, 0.f, 0.f, 0.f};

  for (int k0 = 0; k0 < K; k0 += BK) {
    __syncthreads();
    #pragma unroll
    for (int i = 0; i < AC/NT; ++i) {
      int c = i*NT + tid;
      int row = c >> 2;
      int kg = k0 + ((c & 3) << 3);
      const u16* src = (kg < ksplit) ? (Ab + (size_t)(m0 + row) * lda0 + kg)
                                     : (A1 + (size_t)(m0 + row) * lda1 + (kg - ksplit));
      GLOAD16(src, &As[(i*NT + (wid << 6)) * 8]);
    }
    #pragma unroll
    for (int i = 0; i < BC/NT; ++i) {
      int c = i*NT + tid;
      int row = c >> 2;
      int kg = k0 + ((c & 3) << 3);
      const u16* src = Bb + (size_t)(n0 + row) * ldb + kg;
      GLOAD16(src, &Bs[(i*NT + (wid << 6)) * 8]);
    }
    __syncthreads();
    v8s af[4], bfr[4];
    #pragma unroll
    for (int t = 0; t < 4; t++)
      af[t] = *(const v8s*)&As[(wm*64 + t*16 + lm)*BK + quad*8];
    #pragma unroll
    for (int t = 0; t < 4; t++)
      bfr[t] = *(const v8s*)&Bs[(wn*64 + t*16 + lm)*BK + quad*8];
    #pragma unroll
    for (int i = 0; i < 4; i++)
      #pragma unroll
      for (int j = 0; j < 4; j++)
        acc[i][j] = __builtin_amdgcn_mfma_f32_16x16x32_bf16(af[i], bfr[j], acc[i][j], 0, 0, 0);
  }

  #pragma unroll
  for (int i = 0; i < 4; i++) {
    #pragma unroll
    for (int j = 0; j < 4; j++) {
      int colw = wn*64 + j*16 + lm;
      #pragma unroll
      for (int r = 0; r < 4; r++) {
        int roww = wm*64 + i*16 + quad*4 + r;
        float v = acc[i][j][r];
        if (MODE == 0) {
          Cf[(size_t)(m0 + roww) * ldc + (n0 + colw)] = v;
        } else if (MODE == 1) {
          int col = n0 + colw, row = m0 + roww;
          float g = gate[(((col >> 9) << 2) + (row >> 10)) * 512 + (col & 511)];
          Cf[(size_t)row * ldc + col] = v * g;
        } else {
          int bz = blockIdx.z >> 3, hz = blockIdx.z & 7;
          Cb[(((size_t)(bz << 10) + (m0 + roww)) << 9) + (hz << 6) + colw] = f2bf(v);
        }
      }
    }
  }
}

// ---------------------------------------------------------------------------
// bf16 transpose: src [R][C] -> dst [C][R], batched via blockIdx.z (stride R*C)
// ---------------------------------------------------------------------------
__launch_bounds__(256)
__global__ void transpose_bf16(const u16* __restrict__ src, u16* __restrict__ dst,
                               int R, int C) {
  __shared__ u16 t[64][65];
  const int c0 = blockIdx.x << 6, r0 = blockIdx.y << 6;
  const size_t bo = (size_t)blockIdx.z * R * C;
  const int tx = threadIdx.x & 63, ty = threadIdx.x >> 6;
  #pragma unroll
  for (int i = 0; i < 16; i++) {
    int r = (i << 2) + ty;
    t[r][tx] = src[bo + (size_t)(r0 + r) * C + c0 + tx];
  }
  __syncthreads();
  #pragma unroll
  for (int i = 0; i < 16; i++) {
    int c = (i << 2) + ty;
    dst[bo + (size_t)(c0 + c) * R + r0 + tx] = t[tx][c];
  }
}

// ---------------------------------------------------------------------------
// mask compress: 9 int32 [B,N,N] disjoint masks -> u8 cat (0=none,1=ent,k+2=type k)
// ---------------------------------------------------------------------------
__launch_bounds__(256)
__global__ void mask_compress(const int4* __restrict__ me, const int4* __restrict__ mt,
                              uchar4* __restrict__ cat) {
  const int idx = blockIdx.x * 256 + threadIdx.x;
  int4 e = me[idx];
  int c0 = e.x, c1 = e.y, c2 = e.z, c3 = e.w;
  #pragma unroll
  for (int k = 0; k < 8; k++) {
    int4 m = mt[(size_t)k * 1048576 + idx];
    c0 += (k + 2) * m.x; c1 += (k + 2) * m.y; c2 += (k + 2) * m.z; c3 += (k + 2) * m.w;
  }
  uchar4 o;
  o.x = (unsigned char)c0; o.y = (unsigned char)c1;
  o.z = (unsigned char)c2; o.w = (unsigned char)c3;
  cat[idx] = o;
}

// ---------------------------------------------------------------------------
// gates pipeline, wide-grid GEMV stages (weights stream exactly once).
// A: t1[b][1024] = elu(q[b] @ Wfc)          grid 16  (64 cols/block, k-split 4)
// B: mt[t][b][512] = t1[b] @ wdc[t]         grid (8,2)
// C: gates[t][s][b][512] = mt[t][b] @ Wc_s  grid (8,3,2)
// ---------------------------------------------------------------------------
__launch_bounds__(256)
__global__ void gates_a(const u16* __restrict__ q, const u16* __restrict__ Wfc,
                        float* __restrict__ t1) {
  __shared__ float qs[2048];
  __shared__ float part[4][4][64];
  const int tid = threadIdx.x;
  for (int i = tid; i < 2048; i += 256) qs[i] = bf2f(q[i]);
  __syncthreads();
  const int col = (blockIdx.x << 6) + (tid & 63);
  const int kq = tid >> 6;
  float a0 = 0, a1 = 0, a2 = 0, a3 = 0;
  for (int kk = 0; kk < 128; kk++) {
    int k = kq * 128 + kk;
    float w = bf2f(Wfc[(size_t)k * 1024 + col]);
    a0 += qs[k] * w; a1 += qs[512 + k] * w;
    a2 += qs[1024 + k] * w; a3 += qs[1536 + k] * w;
  }
  part[kq][0][tid & 63] = a0; part[kq][1][tid & 63] = a1;
  part[kq][2][tid & 63] = a2; part[kq][3][tid & 63] = a3;
  __syncthreads();
  const int b = tid >> 6, c = tid & 63;
  float s = part[0][b][c] + part[1][b][c] + part[2][b][c] + part[3][b][c];
  s = s > 0.f ? s : __expf(s) - 1.0f;
  t1[(b << 10) + (blockIdx.x << 6) + c] = s;
}

__launch_bounds__(256)
__global__ void gates_b(const float* __restrict__ t1, const u16* __restrict__ wdc,
                        float* __restrict__ mt) {
  __shared__ float ts[4096];
  __shared__ float part[4][4][64];
  const int tid = threadIdx.x;
  for (int i = tid; i < 4096; i += 256) ts[i] = t1[i];
  __syncthreads();
  const int t = blockIdx.y;
  const int col = (blockIdx.x << 6) + (tid & 63);
  const int kq = tid >> 6;
  float a0 = 0, a1 = 0, a2 = 0, a3 = 0;
  for (int kk = 0; kk < 256; kk++) {
    int k = kq * 256 + kk;
    float w = bf2f(wdc[((size_t)(t << 10) + k) * 512 + col]);
    a0 += ts[k] * w; a1 += ts[1024 + k] * w;
    a2 += ts[2048 + k] * w; a3 += ts[3072 + k] * w;
  }
  part[kq][0][tid & 63] = a0; part[kq][1][tid & 63] = a1;
  part[kq][2][tid & 63] = a2; part[kq][3][tid & 63] = a3;
  __syncthreads();
  const int b = tid >> 6, c = tid & 63;
  float s = part[0][b][c] + part[1][b][c] + part[2][b][c] + part[3][b][c];
  mt[((t * 4 + b) << 9) + (blockIdx.x << 6) + c] = s;
}

__launch_bounds__(256)
__global__ void gates_c(const float* __restrict__ mt,
                        const u16* __restrict__ Wqc, const u16* __restrict__ Wkc,
                        const u16* __restrict__ Wvc, float* __restrict__ gates) {
  __shared__ float ms[2048];
  __shared__ float part[4][4][64];
  const int tid = threadIdx.x;
  const int s_ = blockIdx.y, t = blockIdx.z;
  for (int i = tid; i < 2048; i += 256) ms[i] = mt[(t << 11) + i];
  __syncthreads();
  const u16* W = (s_ == 0) ? Wqc : ((s_ == 1) ? Wkc : Wvc);
  const int col = (blockIdx.x << 6) + (tid & 63);
  const int kq = tid >> 6;
  float a0 = 0, a1 = 0, a2 = 0, a3 = 0;
  for (int kk = 0; kk < 128; kk++) {
    int k = kq * 128 + kk;
    float w = bf2f(W[(size_t)k * 512 + col]);
    a0 += ms[k] * w; a1 += ms[512 + k] * w;
    a2 += ms[1024 + k] * w; a3 += ms[1536 + k] * w;
  }
  part[kq][0][tid & 63] = a0; part[kq][1][tid & 63] = a1;
  part[kq][2][tid & 63] = a2; part[kq][3][tid & 63] = a3;
  __syncthreads();
  const int b = tid >> 6, c = tid & 63;
  float s = part[0][b][c] + part[1][b][c] + part[2][b][c] + part[3][b][c];
  gates[(((t * 3 + s_) * 4 + b) << 9) + (blockIdx.x << 6) + c] = s;
}

// ---------------------------------------------------------------------------
// LayerNorm rows: W = NE*256, segments via blockIdx.y (qkv fusion)
// flags[0]!=0 -> write fp32 to dst; else bf16.
// ---------------------------------------------------------------------------
template<int NE>
__launch_bounds__(256)
__global__ void ln_rows(const float* __restrict__ src, int sstride, int ssegoff,
                        void* __restrict__ dst, int dstride, int dsegoff,
                        const int* __restrict__ flagp,
                        const u16* __restrict__ g0, const u16* __restrict__ b0,
                        const u16* __restrict__ g1, const u16* __restrict__ b1,
                        const u16* __restrict__ g2, const u16* __restrict__ b2) {
  constexpr int W = NE * 256;
  const int row = blockIdx.x, seg = blockIdx.y;
  const u16* g  = (seg == 0) ? g0 : ((seg == 1) ? g1 : g2);
  const u16* bb = (seg == 0) ? b0 : ((seg == 1) ? b1 : b2);
  const float* x = src + (size_t)row * sstride + (size_t)seg * ssegoff;
  const size_t dbase = (size_t)row * dstride + (size_t)seg * dsegoff;
  const int f32out = *flagp;
  const int tid = threadIdx.x;
  const int wid = tid >> 6, lane = tid & 63;
  __shared__ float red[4];
  float v[NE];
  float s = 0.f;
  #pragma unroll
  for (int i = 0; i < NE; i++) { v[i] = x[tid + (i << 8)]; s += v[i]; }
  #pragma unroll
  for (int off = 32; off; off >>= 1) s += __shfl_xor(s, off, 64);
  if (lane == 0) red[wid] = s;
  __syncthreads();
  float mean = (red[0] + red[1] + red[2] + red[3]) * (1.0f / W);
  float q = 0.f;
  #pragma unroll
  for (int i = 0; i < NE; i++) { float dd = v[i] - mean; q += dd * dd; }
  __syncthreads();
  #pragma unroll
  for (int off = 32; off; off >>= 1) q += __shfl_xor(q, off, 64);
  if (lane == 0) red[wid] = q;
  __syncthreads();
  float var = (red[0] + red[1] + red[2] + red[3]) * (1.0f / W);
  float rs = rsqrtf(var + 1e-12f);
  #pragma unroll
  for (int i = 0; i < NE; i++) {
    int c = tid + (i << 8);
    float y = (v[i] - mean) * rs * bf2f(g[c]) + bf2f(bb[c]);
    if (f32out) ((float*)dst)[dbase + c] = y;
    else        ((u16*)dst)[dbase + c] = f2bf(y);
  }
}

// ---------------------------------------------------------------------------
// a_src[b,h,m,n] = sum_d xq[b,n,h*64+d]*Watt[m][d]; a_dst from xk, Watt[m][64+d]
// ---------------------------------------------------------------------------
__launch_bounds__(256)
__global__ void att_proj(const u16* __restrict__ xq, const u16* __restrict__ xk,
                         const u16* __restrict__ Watt,
                         float* __restrict__ asrc, float* __restrict__ adst) {
  __shared__ float w[9][128];
  const int tid = threadIdx.x;
  for (int i = tid; i < 9 * 128; i += 256) w[i / 128][i % 128] = bf2f(Watt[i]);
  __syncthreads();
  const int wid = tid >> 6, lane = tid & 63;
  const int row = blockIdx.x * 4 + wid;
  const int b = row >> 10, n = row & 1023;
  v8s q8 = *(const v8s*)&xq[(size_t)row * 512 + lane * 8];
  v8s k8 = *(const v8s*)&xk[(size_t)row * 512 + lane * 8];
  float qf[8], kf[8];
  #pragma unroll
  for (int j = 0; j < 8; j++) { qf[j] = bf2f((u16)q8[j]); kf[j] = bf2f((u16)k8[j]); }
  const int h = lane >> 3, lh = lane & 7;
  #pragma unroll
  for (int m = 0; m < 9; m++) {
    float ps = 0.f, pd = 0.f;
    #pragma unroll
    for (int j = 0; j < 8; j++) {
      ps += qf[j] * w[m][lh * 8 + j];
      pd += kf[j] * w[m][64 + lh * 8 + j];
    }
    #pragma unroll
    for (int off = 1; off < 8; off <<= 1) {
      ps += __shfl_xor(ps, off, 64);
      pd += __shfl_xor(pd, off, 64);
    }
    if (lh == 0) {
      size_t base = ((size_t)((b * 8 + h) * 9 + m) << 10) + n;
      asrc[base] = ps;
      adst[base] = pd;
    }
  }
}

// ---------------------------------------------------------------------------
// score + masked softmax -> P bf16 [32][1024][1024]
// ---------------------------------------------------------------------------
__launch_bounds__(256)
__global__ void score_softmax(const unsigned char* __restrict__ cat,
                              const float* __restrict__ asrc,
                              const float* __restrict__ adst,
                              u16* __restrict__ P) {
  const int bh = blockIdx.y;
  const int b = bh >> 3;
  const int i0 = blockIdx.x << 6;
  __shared__ float adst_s[9 * 1024];
  __shared__ float asrc_s[64 * 9];
  const int tid = threadIdx.x;
  const float* ad = adst + (size_t)bh * 9216;
  for (int i = tid; i < 9216; i += 256) adst_s[i] = ad[i];
  const float* as = asrc + (size_t)bh * 9216;
  for (int i = tid; i < 576; i += 256) {
    int r = i / 9, m = i % 9;
    asrc_s[i] = as[(m << 10) + i0 + r];
  }
  __syncthreads();
  const int wid = tid >> 6, lane = tid & 63;
  for (int ir = wid; ir < 64; ir += 4) {
    const int i = i0 + ir;
    const unsigned int* crow = (const unsigned int*)(cat + (((size_t)(b << 10) + i) << 10));
    float z[16];
    float mx = -1e30f;
    #pragma unroll
    for (int it = 0; it < 4; it++) {
      unsigned int c4 = crow[(it << 6) + lane];
      int jb = (it << 8) + (lane << 2);
      #pragma unroll
      for (int s = 0; s < 4; s++) {
        int c = (c4 >> (s * 8)) & 255;
        float zz = -1e30f;
        if (c > 0) {
          int m = c - 1;
          float sc = asrc_s[ir * 9 + m] + adst_s[(m << 10) + jb + s];
          zz = (sc > 0.f) ? sc : 0.01f * sc;
          mx = fmaxf(mx, zz);
        }
        z[it * 4 + s] = zz;
      }
    }
    #pragma unroll
    for (int off = 32; off; off >>= 1) mx = fmaxf(mx, __shfl_xor(mx, off, 64));
    float sum = 0.f;
    #pragma unroll
    for (int u = 0; u < 16; u++) {
      float e = (z[u] > -1e29f) ? __expf(z[u] - mx) : 0.f;
      z[u] = e; sum += e;
    }
    #pragma unroll
    for (int off = 32; off; off >>= 1) sum += __shfl_xor(sum, off, 64);
    float inv = 1.0f / (sum + 1e-13f);
    u16* prow = P + (((size_t)bh << 10) + i) * 1024;
    #pragma unroll
    for (int it = 0; it < 4; it++) {
      int jb = (it << 8) + (lane << 2);
      ushort4 o;
      o.x = f2bf(z[it * 4 + 0] * inv);
      o.y = f2bf(z[it * 4 + 1] * inv);
      o.z = f2bf(z[it * 4 + 2] * inv);
      o.w = f2bf(z[it * 4 + 3] * inv);
      *(ushort4*)&prow[jb] = o;
    }
  }
}

// ---------------------------------------------------------------------------
extern "C" void kernel_launch(void* const* d_in, const int* in_sizes, int n_in,
                              void* d_out, int out_size, void* d_ws, size_t ws_size,
                              hipStream_t stream) {
  char* wptr = (char*)d_ws;
  auto alloc = [&](size_t bytes) {
    char* p = wptr; wptr += (bytes + 255) & ~(size_t)255; return p;
  };
  int* flags     = (int*)alloc(256);
  uint8_t* cat   = (uint8_t*)alloc(4ull << 20);
  u16* dwT       = (u16*)alloc(1024ull*1024*2);
  // wqkvT (1536x1024) immediately followed by wuT (512x1024): one batched transpose dst
  u16* wqkvT     = (u16*)alloc(2048ull*1024*2);
  u16* wuT       = wqkvT + 1536*1024;
  float* gates   = (float*)alloc(2ull*3*4*512*4);
  float* t1buf   = (float*)alloc(4096ull*4);
  float* mtbuf   = (float*)alloc(4096ull*4);
  // canonical bf16 copies of the 23 float tensors; Wqv,Wkv,Wvv,Wu contiguous
  static const int cn[NCONV] = {
    2097152, 2048, 524288, 1048576, 1048576, 1024, 1024,
    524288, 524288, 524288, 262144, 262144, 262144,
    512, 512, 512, 512, 512, 512, 1152, 524288, 512, 512 };
  u16* canon[NCONV];
  u16* wvblock = (u16*)alloc(4ull * 524288 * 2);   // [Wqv|Wkv|Wvv|Wu]
  for (int i = 0; i < NCONV; i++) {
    if (i == 7 || i == 8 || i == 9) canon[i] = wvblock + (size_t)(i - 7) * 524288;
    else if (i == 20)               canon[i] = wvblock + 3ull * 524288;
    else                            canon[i] = (u16*)alloc((size_t)cn[i] * 2);
  }
  // 64 MB union: ie_pre/qkv_pre/ie (phase 1) -> P (phase 2) -> u_pre (phase 3)
  char* U = alloc(64ull << 20);
  float* ie_pre  = (float*)U;                       // 16 MB
  float* qkv_pre = (float*)(U + (16ull << 20));     // 24 MB
  u16*   ie      = (u16*)(U + (40ull << 20));       //  8 MB
  u16*   P       = (u16*)U;                         // 64 MB
  float* u_pre   = (float*)U;                       //  8 MB
  u16* xqkv      = (u16*)alloc(3ull*4096*512*2);
  float* asrc    = (float*)alloc(32ull*9*1024*4);
  float* adst    = (float*)alloc(32ull*9*1024*4);
  u16* xvT       = (u16*)alloc(32ull*64*1024*2);
  u16* xcat      = (u16*)alloc(4096ull*512*2);
  u16* node_enc  = (u16*)alloc(4096ull*512*2);

  const int* mask_e = (const int*)d_in[23];
  const int* mask_t = (const int*)d_in[24];

  detect_dtype<<<1, 64, 0, stream>>>((const u16*)d_in[5], flags);

  ConvTab tab;
  for (int i = 0; i < NCONV; i++) {
    tab.src[i] = d_in[i]; tab.dst[i] = canon[i]; tab.n[i] = cn[i];
  }
  convert_inputs<<<dim3(64, NCONV), 256, 0, stream>>>(tab, flags);

  const u16* c_node = canon[0];
  const u16* c_q    = canon[1];
  const u16* c_Wfc  = canon[2];
  const u16* c_wdc  = canon[3];
  const u16* c_dw   = canon[4];
  const u16 *c_lin_g = canon[5], *c_lin_b = canon[6];
  const u16 *c_Wqc = canon[10], *c_Wkc = canon[11], *c_Wvc = canon[12];
  const u16 *c_lq_g = canon[13], *c_lq_b = canon[14];
  const u16 *c_lk_g = canon[15], *c_lk_b = canon[16];
  const u16 *c_lv_g = canon[17], *c_lv_b = canon[18];
  const u16* c_Watt = canon[19];
  const u16 *c_lo_g = canon[21], *c_lo_b = canon[22];

  mask_compress<<<4096, 256, 0, stream>>>((const int4*)mask_e, (const int4*)mask_t,
                                          (uchar4*)cat);
  transpose_bf16<<<dim3(16,16,1), 256, 0, stream>>>(c_dw, dwT, 1024, 1024);
  // [Wqv|Wkv|Wvv|Wu] (contiguous) -> [wqkvT|wuT] (contiguous), one batched launch
  transpose_bf16<<<dim3(8,16,4),  256, 0, stream>>>(wvblock, wqkvT, 1024, 512);
  gates_a<<<16, 256, 0, stream>>>(c_q, c_Wfc, t1buf);
  gates_b<<<dim3(8,2), 256, 0, stream>>>(t1buf, c_wdc, mtbuf);
  gates_c<<<dim3(8,3,2), 256, 0, stream>>>(mtbuf, c_Wqc, c_Wkc, c_Wvc, gates);

  const u16* ne_cur = c_node;
  for (int t = 0; t < 2; ++t) {
    gemm_bt<2,2,0><<<dim3(32,8,1), 256, 0, stream>>>(
        ne_cur, 512, c_node, 512, 512, dwT, 1024,
        ie_pre, (u16*)nullptr, 1024, 1024, (const float*)nullptr, 0, 0);
    ln_rows<4><<<dim3(4096,1), 256, 0, stream>>>(
        ie_pre, 1024, 0, ie, 1024, 0, flags + 1,
        c_lin_g, c_lin_b, c_lin_g, c_lin_b, c_lin_g, c_lin_b);
    gemm_bt<2,2,1><<<dim3(32,12,1), 256, 0, stream>>>(
        ie, 1024, ie, 1024, 1024, wqkvT, 1024,
        qkv_pre, (u16*)nullptr, 1536, 1024, gates + t*6144, 0, 0);
    ln_rows<2><<<dim3(4096,3), 256, 0, stream>>>(
        qkv_pre, 1536, 512, xqkv, 512, 4096*512, flags + 1,
        c_lq_g, c_lq_b, c_lk_g, c_lk_b, c_lv_g, c_lv_b);
    att_proj<<<1024, 256, 0, stream>>>(xqkv, xqkv + 4096*512, c_Watt, asrc, adst);
    transpose_bf16<<<dim3(8,16,4), 256, 0, stream>>>(xqkv + 2*4096*512, xvT, 1024, 512);
    score_softmax<<<dim3(16,32,1), 256, 0, stream>>>(cat, asrc, adst, P);
    gemm_bt<2,1,2><<<dim3(8,1,32), 128, 0, stream>>>(
        P, 1024, P, 1024, 1024, xvT, 1024,
        (float*)nullptr, xcat, 512, 1024, (const float*)nullptr, 1048576, 65536);
    gemm_bt<2,1,0><<<dim3(32,8,1), 128, 0, stream>>>(
        ne_cur, 512, xcat, 512, 512, wuT, 1024,
        u_pre, (u16*)nullptr, 512, 1024, (const float*)nullptr, 0, 0);
    void* dst = (t == 1) ? d_out : (void*)node_enc;
    const int* fl = (t == 1) ? flags : (flags + 1);
    ln_rows<2><<<dim3(4096,1), 256, 0, stream>>>(
        u_pre, 512, 0, dst, 512, 0, fl,
        c_lo_g, c_lo_b, c_lo_g, c_lo_b, c_lo_g, c_lo_b);
    ne_cur = node_enc;
  }
  (void)in_sizes; (void)n_in; (void)out_size; (void)ws_size;
}